// Round 5
// baseline (507.362 us; speedup 1.0000x reference)
//
#include <hip/hip_runtime.h>
#include <hip/hip_bf16.h>

// Problem constants
#define DM   1024   // d_model
#define NH   16     // heads
#define DH   64     // depth per head
#define BB   4      // batch
#define SS   2048   // seq len
// tokens N = BB*SS = 8192

typedef __attribute__((ext_vector_type(8))) short bf16x8;   // 8 bf16 (4 VGPRs) - MFMA A/B frag
typedef __attribute__((ext_vector_type(4))) float f32x4;    // MFMA C/D frag

static __device__ __forceinline__ unsigned short f2bf(float f) {
  union { float f; unsigned u; } v; v.f = f;
  unsigned r = v.u + 0x7fffu + ((v.u >> 16) & 1u);   // RNE
  return (unsigned short)(r >> 16);
}

// pack two f32 -> one u32 of 2 bf16 (lo in [15:0])  [T12 recipe, guide-verified]
static __device__ __forceinline__ unsigned cvtpk(float lo, float hi) {
  unsigned r;
  asm("v_cvt_pk_bf16_f32 %0, %1, %2" : "=v"(r) : "v"(lo), "v"(hi));
  return r;
}

// async global->LDS, 16B per lane. LDS dest resolves to wave-uniform base + lane*16.
static __device__ __forceinline__ void gload16(const void* g, void* l) {
  __builtin_amdgcn_global_load_lds((const __attribute__((address_space(1))) void*)g,
                                   (__attribute__((address_space(3))) void*)l, 16, 0, 0);
}

union UV { unsigned u[4]; bf16x8 v; };

// ---------------------------------------------------------------------------
// Weight transpose+convert, all four weights in one launch:
// W f32 [k=1024][n=1024] -> Wt bf16 [n][k], GEMM B-tile XOR-swizzle PRE-APPLIED:
// within each 64-k segment, logical chunk c of 8 bf16 stored at c ^ (n&7).
// grid 1024 blocks (4 weights x 256 tiles of 64x64), 256 threads
// ---------------------------------------------------------------------------
__global__ __launch_bounds__(256) void wt_conv4(const float* __restrict__ W0,
                                                const float* __restrict__ W1,
                                                const float* __restrict__ W2,
                                                const float* __restrict__ W3,
                                                unsigned short* __restrict__ T0,
                                                unsigned short* __restrict__ T1,
                                                unsigned short* __restrict__ T2,
                                                unsigned short* __restrict__ T3) {
  __shared__ unsigned short t[64][72];
  int which = blockIdx.x >> 8;
  const float* W = (which == 0) ? W0 : (which == 1) ? W1 : (which == 2) ? W2 : W3;
  unsigned short* Wt = (which == 0) ? T0 : (which == 1) ? T1 : (which == 2) ? T2 : T3;
  int bid = blockIdx.x & 255;
  int tid = threadIdx.x;
  int k0 = (bid >> 4) << 6;
  int n0 = (bid & 15) << 6;
  #pragma unroll
  for (int i = 0; i < 4; ++i) {
    int u = tid + (i << 8);
    int row = u >> 4, nc = u & 15;               // row = k index, nc = 4-float chunk
    const float4* p = (const float4*)(W + (size_t)(k0 + row) * DM + n0 + (nc << 2));
    float4 x = *p;
    t[row][(nc << 2) + 0] = f2bf(x.x);
    t[row][(nc << 2) + 1] = f2bf(x.y);
    t[row][(nc << 2) + 2] = f2bf(x.z);
    t[row][(nc << 2) + 3] = f2bf(x.w);
  }
  __syncthreads();
  #pragma unroll
  for (int i = 0; i < 2; ++i) {
    int u = tid + (i << 8);
    int kc = u & 7, n = u >> 3;                  // n row, kc = 8-elem chunk along k
    bf16x8 v;
    #pragma unroll
    for (int j = 0; j < 8; ++j) v[j] = (short)t[(kc << 3) + j][n];
    *(bf16x8*)(Wt + (size_t)(n0 + n) * DM + k0 + ((kc ^ (n & 7)) << 3)) = v;
  }
}

// ---------------------------------------------------------------------------
// GEMM: Y[8192 x 1024] = X[8192 x 1024] * W + bias
//   Wt bf16 [n][k] pre-swizzled.  BM=BN=128, BK=64, 4 waves (2x2).
//   OUT_MODE 0: bf16 head-split [b,h,s,64], attn chunk-swizzle pre-applied.
//               (swapped MFMA: A=W,B=X -> quad = 4 consecutive n)
//   OUT_MODE 1: fp32 flat [m][n].          (swapped MFMA, float4 stores)
//   OUT_MODE 2: bf16 Vt [bh*64+d][s=2048], attn V chunk-swizzle pre-applied.
//               (non-swapped MFMA: A=X,B=W -> quad = 4 consecutive tokens)
//   IN_F32=1: X fp32, reg-staged + converted; prefetched across the barrier.
//   IN_F32=0: X bf16 pre-swizzled -> staged via global_load_lds.
// ---------------------------------------------------------------------------
template <int IN_F32, int OUT_MODE>
__global__ __launch_bounds__(256) void gemm128(const void* __restrict__ Xv,
                                               const unsigned short* __restrict__ Wt,
                                               const float* __restrict__ bias,
                                               void* __restrict__ Yv) {
  constexpr bool SWAP = (OUT_MODE != 2);             // quad = n-dim if swapped, m-dim else
  __shared__ __align__(16) unsigned char As[16384];  // [128 rows][8 chunks of 16B], swizzled content
  __shared__ __align__(16) unsigned char Bs[16384];
  int tid = threadIdx.x;
  int lane = tid & 63, w = tid >> 6;
  int g = lane >> 4, l15 = lane & 15;
  int bid = blockIdx.x;
  int sw = ((bid & 7) << 6) + (bid >> 3);            // XCD-bijective swizzle (512 blocks)
  int m0 = (sw >> 3) << 7;
  int n0 = (sw & 7) << 7;
  int wr = w >> 1, wc = w & 1;

  f32x4 acc[4][4];
  #pragma unroll
  for (int a = 0; a < 4; ++a)
    #pragma unroll
    for (int b2 = 0; b2 < 4; ++b2)
      #pragma unroll
      for (int r = 0; r < 4; ++r) acc[a][b2][r] = 0.0f;

  float4 pa0[4], pa1[4];                             // fp32 A prefetch regs
  if (IN_F32) {
    #pragma unroll
    for (int i = 0; i < 4; ++i) {
      int u = tid + (i << 8);
      int row = u >> 3, ch = u & 7;
      const float4* p = (const float4*)((const float*)Xv + (size_t)(m0 + row) * DM + (ch << 3));
      pa0[i] = p[0]; pa1[i] = p[1];
    }
  }

  const int NK = DM / 64;
  for (int t = 0; t < NK; ++t) {
    int k0 = t << 6;
    // ---- stage phase ----
    #pragma unroll
    for (int i = 0; i < 4; ++i) {
      int u = tid + (i << 8);
      int row = u >> 3, ch = u & 7;
      if (IN_F32) {
        bf16x8 aval;
        float4 x0 = pa0[i], x1 = pa1[i];
        aval[0] = (short)f2bf(x0.x); aval[1] = (short)f2bf(x0.y);
        aval[2] = (short)f2bf(x0.z); aval[3] = (short)f2bf(x0.w);
        aval[4] = (short)f2bf(x1.x); aval[5] = (short)f2bf(x1.y);
        aval[6] = (short)f2bf(x1.z); aval[7] = (short)f2bf(x1.w);
        *(bf16x8*)(As + row * 128 + ((ch ^ (row & 7)) << 4)) = aval;
      } else {
        gload16((const unsigned short*)Xv + ((size_t)(m0 + row) << 10) + k0 + (ch << 3),
                As + u * 16);
      }
      gload16(Wt + ((size_t)(n0 + row) << 10) + k0 + (ch << 3), Bs + u * 16);
    }
    __syncthreads();                                  // drains DMA + LDS writes
    if (IN_F32 && t + 1 < NK) {
      int k1 = (t + 1) << 6;
      #pragma unroll
      for (int i = 0; i < 4; ++i) {
        int u = tid + (i << 8);
        int row = u >> 3, ch = u & 7;
        const float4* p = (const float4*)((const float*)Xv + (size_t)(m0 + row) * DM + k1 + (ch << 3));
        pa0[i] = p[0]; pa1[i] = p[1];                 // latency hides under MFMA
      }
    }
    // ---- MFMA phase ----
    #pragma unroll
    for (int ks = 0; ks < 2; ++ks) {
      bf16x8 af[4], bfr[4];
      #pragma unroll
      for (int mf = 0; mf < 4; ++mf) {
        int row = (wr << 6) + (mf << 4) + l15;
        af[mf] = *(const bf16x8*)(As + row * 128 + ((((ks << 2) + g) ^ (row & 7)) << 4));
      }
      #pragma unroll
      for (int nf = 0; nf < 4; ++nf) {
        int row = (wc << 6) + (nf << 4) + l15;
        bfr[nf] = *(const bf16x8*)(Bs + row * 128 + ((((ks << 2) + g) ^ (row & 7)) << 4));
      }
      #pragma unroll
      for (int mf = 0; mf < 4; ++mf)
        #pragma unroll
        for (int nf = 0; nf < 4; ++nf) {
          if (SWAP)   // acc = Y^T tile: [n: g*4+r][m: l15]
            acc[mf][nf] = __builtin_amdgcn_mfma_f32_16x16x32_bf16(bfr[nf], af[mf], acc[mf][nf], 0, 0, 0);
          else        // acc = Y tile:   [m: g*4+r][n: l15]
            acc[mf][nf] = __builtin_amdgcn_mfma_f32_16x16x32_bf16(af[mf], bfr[nf], acc[mf][nf], 0, 0, 0);
        }
    }
    __syncthreads();                                  // reads done -> safe to overwrite
  }

  // ---- epilogue ----
  if (OUT_MODE == 2) {
    // acc[mf][nf][r] = Y[m = m0+wr*64+mf*16+g*4+r][n = n0+wc*64+nf*16+l15]
    #pragma unroll
    for (int nf = 0; nf < 4; ++nf) {
      int n = n0 + (wc << 6) + (nf << 4) + l15;
      float bv = bias[n];
      int h = n >> 6, d = n & 63;
      #pragma unroll
      for (int mf = 0; mf < 4; ++mf) {
        int mq = m0 + (wr << 6) + (mf << 4) + (g << 2);   // token base of the quad
        int b = mq >> 11, s = mq & (SS - 1);
        int sc3 = (s >> 3) & 7;                           // logical 8-token chunk in segment
        unsigned long long val = (unsigned long long)cvtpk(acc[mf][nf][0] + bv, acc[mf][nf][1] + bv)
                               | ((unsigned long long)cvtpk(acc[mf][nf][2] + bv, acc[mf][nf][3] + bv) << 32);
        size_t byteoff = ((size_t)(((b << 4) + h) * DH + d) << 12)   // Vt row (bh*64+d) * 4096B
                       + ((size_t)(s >> 6) << 7)                      // 64-token segment
                       + ((size_t)(sc3 ^ (d & 7)) << 4) + ((size_t)(g & 1) << 3);
        *(unsigned long long*)((unsigned char*)Yv + byteoff) = val;
      }
    }
  } else {
    // acc[mf][nf][r] = Y[m = m0+wr*64+mf*16+l15][n = n0+wc*64+nf*16+g*4+r]
    #pragma unroll
    for (int mf = 0; mf < 4; ++mf) {
      int m = m0 + (wr << 6) + (mf << 4) + l15;
      #pragma unroll
      for (int nf = 0; nf < 4; ++nf) {
        int nb = n0 + (wc << 6) + (nf << 4) + (g << 2);
        float4 bv4 = *(const float4*)(bias + nb);
        float v0 = acc[mf][nf][0] + bv4.x;
        float v1 = acc[mf][nf][1] + bv4.y;
        float v2 = acc[mf][nf][2] + bv4.z;
        float v3 = acc[mf][nf][3] + bv4.w;
        if (OUT_MODE == 0) {
          int b = m >> 11, s = m & (SS - 1);
          int h = nb >> 6;                              // head
          int c = (nf << 1) + (g >> 1);                 // logical 8-elem chunk within head
          unsigned long long val = (unsigned long long)cvtpk(v0, v1)
                                 | ((unsigned long long)cvtpk(v2, v3) << 32);
          size_t byteoff = (((size_t)((b << 4) + h) * SS + s) << 7)
                         + ((size_t)(c ^ (s & 7)) << 4) + ((size_t)(g & 1) << 3);
          *(unsigned long long*)((unsigned char*)Yv + byteoff) = val;
        } else {
          *(float4*)((float*)Yv + (size_t)m * DM + nb) = make_float4(v0, v1, v2, v3);
        }
      }
    }
  }
}

// ---------------------------------------------------------------------------
// Flash attention, swapped-QK^T, 4-shfl relay P-exchange, 64 q-rows per wave.
// grid = 64 bh * 8 q-tiles = 512 blocks, 256 threads (4 waves x 64 q-rows).
// Qh/Kh bf16 [bh][s][64] pre-swizzled; Vt bf16 [bh][d][s] pre-swizzled.
// ctx out bf16 [b][s][1024] pre-swizzled for the Wo gemm's global_load_lds.
// ---------------------------------------------------------------------------
__global__ __launch_bounds__(256) void attn128(const unsigned short* __restrict__ Qh,
                                               const unsigned short* __restrict__ Kh,
                                               const unsigned short* __restrict__ Vt,
                                               const int* __restrict__ mask,
                                               unsigned short* __restrict__ ctx) {
  __shared__ __align__(16) unsigned char KsB[2][8192];   // [kv 64][d chunks], dbuf
  __shared__ __align__(16) unsigned char VsB[2][8192];   // [d 64][kv chunks], dbuf
  int tid = threadIdx.x;
  int lane = tid & 63, w = tid >> 6;
  int g = lane >> 4, l15 = lane & 15;
  int bid = blockIdx.x;
  int sw = ((bid & 7) << 6) + (bid >> 3);                // XCD-bijective (512 blocks)
  int bh = sw >> 3, qt = sw & 7;
  int b = bh >> 4, h = bh & 15;
  int q0w = (qt << 8) + (w << 6);                        // wave's 64 q rows

  const unsigned short* Qbase = Qh + ((size_t)bh * SS << 6);
  const unsigned short* Kbase = Kh + ((size_t)bh * SS << 6);
  const unsigned short* Vbase = Vt + (size_t)bh * DH * SS;
  const int* maskB = mask + b * SS;

  // Q fragments in registers for the whole kernel (Q is the MFMA B-operand).
  bf16x8 aq[4][2];
  #pragma unroll
  for (int set = 0; set < 4; ++set) {
    int q = q0w + (set << 4) + l15;
    #pragma unroll
    for (int ks = 0; ks < 2; ++ks)
      aq[set][ks] = *(const bf16x8*)(Qbase + ((size_t)q << 6) + ((((ks << 2) + g) ^ (q & 7)) << 3));
  }

  float mr[4] = {-1e30f, -1e30f, -1e30f, -1e30f};
  float lr[4] = {0.0f, 0.0f, 0.0f, 0.0f};
  f32x4 O[4][4];
  #pragma unroll
  for (int set = 0; set < 4; ++set)
    #pragma unroll
    for (int fd = 0; fd < 4; ++fd)
      #pragma unroll
      for (int r = 0; r < 4; ++r) O[set][fd][r] = 0.0f;

  auto stage = [&](int t2, int buf2) {
    int kv0 = t2 << 6;
    unsigned char* Kd = (unsigned char*)KsB[buf2];
    unsigned char* Vd = (unsigned char*)VsB[buf2];
    #pragma unroll
    for (int i = 0; i < 2; ++i) {
      int u = tid + (i << 8);
      int row = u >> 3, ch = u & 7;
      gload16(Kbase + ((size_t)(kv0 + row) << 6) + (ch << 3), Kd + u * 16);
      gload16(Vbase + (size_t)row * SS + kv0 + (ch << 3), Vd + u * 16);
    }
  };

  stage(0, 0);

  const int NT = SS / 64;
  for (int t = 0; t < NT; ++t) {
    __syncthreads();                 // vmcnt drained -> buf[t&1] ready; other buf free
    int buf = t & 1;
    if (t + 1 < NT) stage(t + 1, buf ^ 1);   // issue early; hides under compute

    // mask -> f32 regs (L2-hot after the first q-tile block of this batch)
    float mb[4][4];
    #pragma unroll
    for (int fc = 0; fc < 4; ++fc) {
      int4 mi = *(const int4*)(maskB + (t << 6) + (fc << 4) + (g << 2));
      mb[fc][0] = -1e9f * (float)mi.x;
      mb[fc][1] = -1e9f * (float)mi.y;
      mb[fc][2] = -1e9f * (float)mi.z;
      mb[fc][3] = -1e9f * (float)mi.w;
    }

    const unsigned char* Kd = (const unsigned char*)KsB[buf];
    const unsigned char* Vd = (const unsigned char*)VsB[buf];

    // K fragments (A-operand): K[kv = fc*16+l15][d-chunk ks*4+g]
    bf16x8 kf[4][2];
    #pragma unroll
    for (int fc = 0; fc < 4; ++fc) {
      int row = (fc << 4) + l15;
      #pragma unroll
      for (int ks = 0; ks < 2; ++ks)
        kf[fc][ks] = *(const bf16x8*)(Kd + row * 128 + ((((ks << 2) + g) ^ (row & 7)) << 4));
    }
    // V fragments (A-operand): V^T[d = fd*16+l15][kv-chunk ks*4+g]
    bf16x8 vf[4][2];
    #pragma unroll
    for (int fd = 0; fd < 4; ++fd) {
      int row = (fd << 4) + l15;
      #pragma unroll
      for (int ks = 0; ks < 2; ++ks)
        vf[fd][ks] = *(const bf16x8*)(Vd + row * 128 + ((((ks << 2) + g) ^ (row & 7)) << 4));
    }

    #pragma unroll
    for (int set = 0; set < 4; ++set) {
      // S^T tile: rows kv (fc*16 + g*4 + r), cols q (l15)
      f32x4 sc[4];
      #pragma unroll
      for (int fc = 0; fc < 4; ++fc) {
        #pragma unroll
        for (int r = 0; r < 4; ++r) sc[fc][r] = 0.0f;
        sc[fc] = __builtin_amdgcn_mfma_f32_16x16x32_bf16(kf[fc][0], aq[set][0], sc[fc], 0, 0, 0);
        sc[fc] = __builtin_amdgcn_mfma_f32_16x16x32_bf16(kf[fc][1], aq[set][1], sc[fc], 0, 0, 0);
      }
      // scale + mask + tile max (row q = l15; reduce regs then g-groups)
      float tmax = -3e38f;
      #pragma unroll
      for (int fc = 0; fc < 4; ++fc)
        #pragma unroll
        for (int r = 0; r < 4; ++r) {
          float s2 = sc[fc][r] * 0.125f + mb[fc][r];
          sc[fc][r] = s2;
          tmax = fmaxf(tmax, s2);
        }
      tmax = fmaxf(tmax, __shfl_xor(tmax, 16, 64));
      tmax = fmaxf(tmax, __shfl_xor(tmax, 32, 64));
      // defer-max (T13): only rescale when some row's max grew past THR=8
      if (!__all(tmax - mr[set] <= 8.0f)) {
        float mnew = fmaxf(mr[set], tmax);
        float fac = __expf(mr[set] - mnew);
        mr[set] = mnew;
        lr[set] *= fac;
        #pragma unroll
        for (int fd = 0; fd < 4; ++fd)
          #pragma unroll
          for (int r = 0; r < 4; ++r) O[set][fd][r] *= fac;
      }
      float rsum = 0.0f;
      #pragma unroll
      for (int fc = 0; fc < 4; ++fc)
        #pragma unroll
        for (int r = 0; r < 4; ++r) {
          float p = __expf(sc[fc][r] - mr[set]);
          sc[fc][r] = p;
          rsum += p;
        }
      rsum += __shfl_xor(rsum, 16, 64);
      rsum += __shfl_xor(rsum, 32, 64);
      lr[set] += rsum;

      // pack P rows to bf16 pairs: w0/w1[fc] = kv (fc*16+g*4) +{0,1}/{2,3}
      unsigned w0[4], w1[4];
      #pragma unroll
      for (int fc = 0; fc < 4; ++fc) {
        w0[fc] = cvtpk(sc[fc][0], sc[fc][1]);
        w1[fc] = cvtpk(sc[fc][2], sc[fc][3]);
      }
      // 4-shfl relay exchange: lane (g,l15) ends with P[q=l15][kv = ks*32+g*8 .. +7].
      // Targets (per ks; A=w0[2ks],B=w1[2ks],C=w0[2ks+1],D=w1[2ks+1]; X_g = from lane-group g):
      //   g0:{A0,B0,A1,B1} g1:{A2,B2,A3,B3} g2:{C0,D0,C1,D1} g3:{C2,D2,C3,D3}
      // Stage A (xor32): send partner-fc own words; Stage B (xor16): relay or own-fc.
      unsigned pa[2][4];
      #pragma unroll
      for (int ks = 0; ks < 2; ++ks) {
        unsigned ownE0 = w0[ks * 2],     ownE1 = w1[ks * 2];
        unsigned ownO0 = w0[ks * 2 + 1], ownO1 = w1[ks * 2 + 1];
        unsigned sA0 = (g & 2) ? ownE0 : ownO0;
        unsigned sA1 = (g & 2) ? ownE1 : ownO1;
        unsigned rA0 = (unsigned)__shfl_xor((int)sA0, 32, 64);
        unsigned rA1 = (unsigned)__shfl_xor((int)sA1, 32, 64);
        bool k03 = (g == 0) || (g == 3);
        unsigned sB0 = k03 ? rA0 : ((g == 1) ? ownE0 : ownO0);
        unsigned sB1 = k03 ? rA1 : ((g == 1) ? ownE1 : ownO1);
        unsigned rB0 = (unsigned)__shfl_xor((int)sB0, 16, 64);
        unsigned rB1 = (unsigned)__shfl_xor((int)sB1, 16, 64);
        pa[ks][0] = (g == 0) ? ownE0 : (g == 2) ? rA0 : rB0;
        pa[ks][1] = (g == 0) ? ownE1 : (g == 2) ? rA1 : rB1;
        pa[ks][2] = (g == 3) ? ownO0 : (g == 1) ? rA0 : rB0;
        pa[ks][3] = (g == 3) ? ownO1 : (g == 1) ? rA1 : rB1;
      }
      // PV for this set: O^T[d][q] += V^T . P^T
      #pragma unroll
      for (int ks = 0; ks < 2; ++ks) {
        UV pv;
        pv.u[0] = pa[ks][0]; pv.u[1] = pa[ks][1];
        pv.u[2] = pa[ks][2]; pv.u[3] = pa[ks][3];
        #pragma unroll
        for (int fd = 0; fd < 4; ++fd)
          O[set][fd] = __builtin_amdgcn_mfma_f32_16x16x32_bf16(vf[fd][ks], pv.v, O[set][fd], 0, 0, 0);
      }
    }
  }

  // epilogue: O^T lane holds (d = fd*16 + g*4 + r, q = q0w + set*16 + l15)
  #pragma unroll
  for (int set = 0; set < 4; ++set) {
    float inv = 1.0f / lr[set];
    int q = q0w + (set << 4) + l15;
    #pragma unroll
    for (int fd = 0; fd < 4; ++fd) {
      unsigned long long val = (unsigned long long)cvtpk(O[set][fd][0] * inv, O[set][fd][1] * inv)
                             | ((unsigned long long)cvtpk(O[set][fd][2] * inv, O[set][fd][3] * inv) << 32);
      int c = (fd << 1) + (g >> 1);                       // d-chunk within the head's 128B seg
      size_t byteoff = (((size_t)(b * SS + q)) << 11) + (h << 7) +
                       ((size_t)(c ^ (q & 7)) << 4) + ((size_t)(g & 1) << 3);
      *(unsigned long long*)((unsigned char*)ctx + byteoff) = val;
    }
  }
}

// ---------------------------------------------------------------------------
extern "C" void kernel_launch(void* const* d_in, const int* in_sizes, int n_in,
                              void* d_out, int out_size, void* d_ws, size_t ws_size,
                              hipStream_t stream) {
  const float* v    = (const float*)d_in[0];
  const float* k    = (const float*)d_in[1];
  const float* q    = (const float*)d_in[2];
  const int*   mask = (const int*)d_in[3];
  const float* Wq   = (const float*)d_in[4];
  const float* bq   = (const float*)d_in[5];
  const float* Wk   = (const float*)d_in[6];
  const float* bk   = (const float*)d_in[7];
  const float* Wv   = (const float*)d_in[8];
  const float* bv   = (const float*)d_in[9];
  const float* Wo   = (const float*)d_in[10];
  const float* bo   = (const float*)d_in[11];

  unsigned char* ws = (unsigned char*)d_ws;
  const size_t MB = 1024ull * 1024ull;
  unsigned short* Wqt = (unsigned short*)(ws + 0 * MB);
  unsigned short* Wkt = (unsigned short*)(ws + 2 * MB);
  unsigned short* Wvt = (unsigned short*)(ws + 4 * MB);
  unsigned short* Wot = (unsigned short*)(ws + 6 * MB);
  unsigned short* Qh  = (unsigned short*)(ws + 8 * MB);   // 16MB  [bh][s][64] swizzled
  unsigned short* Kh  = (unsigned short*)(ws + 24 * MB);  // 16MB  [bh][s][64] swizzled
  unsigned short* Vt  = (unsigned short*)(ws + 40 * MB);  // 16MB  [bh*64+d][s] swizzled
  unsigned short* ctx = (unsigned short*)(ws + 56 * MB);  // 16MB  [b][s][1024] swizzled

  wt_conv4<<<1024, 256, 0, stream>>>(Wq, Wk, Wv, Wo, Wqt, Wkt, Wvt, Wot);

  gemm128<1, 0><<<512, 256, 0, stream>>>((const void*)q, Wqt, bq, (void*)Qh);
  gemm128<1, 0><<<512, 256, 0, stream>>>((const void*)k, Wkt, bk, (void*)Kh);
  gemm128<1, 2><<<512, 256, 0, stream>>>((const void*)v, Wvt, bv, (void*)Vt);

  attn128<<<512, 256, 0, stream>>>(Qh, Kh, Vt, mask, (unsigned short*)ctx);

  gemm128<0, 1><<<512, 256, 0, stream>>>((const void*)ctx, Wot, bo, d_out);
}